// Round 4
// baseline (759.851 us; speedup 1.0000x reference)
//
#include <hip/hip_runtime.h>
#include <hip/hip_bf16.h>
#include <stdint.h>

#define NN 50000
#define NE 400000
#define CIN 256
#define HID 512
#define COUT 128
#define NG 64
#define SCAN_NB ((NN + 255) / 256)   // 196
#define MT_TILES ((NN + 255) / 256)  // 196 M-tiles of 256 rows
#define GEMM_NWG (MT_TILES * 4)      // 784, divisible by 8

typedef short bf16x8 __attribute__((ext_vector_type(8)));
typedef float f32x4 __attribute__((ext_vector_type(4)));

__device__ inline float bf2f(unsigned short u) {
    union { unsigned int i; float f; } v; v.i = ((unsigned int)u) << 16; return v.f;
}
__device__ inline unsigned short f2bf(float f) {
    union { float f; unsigned int u; } v; v.f = f;
    unsigned int r = v.u + 0x7fffu + ((v.u >> 16) & 1u);
    return (unsigned short)(r >> 16);
}

__device__ inline void async16(const void* g, void* l) {
    __builtin_amdgcn_global_load_lds((const __attribute__((address_space(1))) void*)g,
                                     (__attribute__((address_space(3))) void*)l, 16, 0, 0);
}

// ---------------- small prep kernels ----------------

__global__ void k_f32_to_bf16(const float* __restrict__ in, unsigned short* __restrict__ out, int n4) {
    int i = blockIdx.x * blockDim.x + threadIdx.x;
    if (i < n4) {
        float4 v = ((const float4*)in)[i];
        ushort4 o;
        o.x = f2bf(v.x); o.y = f2bf(v.y); o.z = f2bf(v.z); o.w = f2bf(v.w);
        ((ushort4*)out)[i] = o;
    }
}

// in: [K][N] f32 row-major -> out: [N][K] bf16
__global__ void k_transpose_cvt(const float* __restrict__ in, unsigned short* __restrict__ out, int K, int N) {
    __shared__ float tile[32][33];
    int bx = blockIdx.x * 32, by = blockIdx.y * 32;
    int tx = threadIdx.x & 31, ty = threadIdx.x >> 5; // 256 thr: ty 0..7
    for (int i = 0; i < 32; i += 8)
        tile[ty + i][tx] = in[(size_t)(by + ty + i) * N + bx + tx];
    __syncthreads();
    for (int i = 0; i < 32; i += 8)
        out[(size_t)(bx + ty + i) * K + by + tx] = f2bf(tile[tx][ty + i]);
}

// per-column fused scale/shift for the 5 GEMM epilogues
__global__ void k_affine(const float* __restrict__ enc_b,
                         const float* __restrict__ cb0, const float* __restrict__ bg0, const float* __restrict__ bb0,
                         const float* __restrict__ cb1, const float* __restrict__ bg1, const float* __restrict__ bb1,
                         float* __restrict__ scale, float* __restrict__ shift) {
    int c = threadIdx.x; // 512
    const float inv = 0.9999950000374997f; // 1/sqrt(1+1e-5)
    scale[c] = 1.f; shift[c] = enc_b[c];
    for (int l = 0; l < 2; l++) {
        float s0 = bg0[l * HID + c] * inv;
        scale[(1 + 2 * l) * HID + c] = s0;
        shift[(1 + 2 * l) * HID + c] = cb0[l * HID + c] * s0 + bb0[l * HID + c];
        float s1 = bg1[l * HID + c] * inv;
        scale[(2 + 2 * l) * HID + c] = s1;
        shift[(2 + 2 * l) * HID + c] = cb1[l * HID + c] * s1 + bb1[l * HID + c];
    }
}

// ---------------- CSR build ----------------

__global__ void k_hist(const int* __restrict__ dst, int* __restrict__ indeg, int n) {
    int i = blockIdx.x * blockDim.x + threadIdx.x;
    if (i < n) atomicAdd(&indeg[dst[i]], 1);
}

__global__ void k_scan1(const int* __restrict__ indeg, int* __restrict__ local,
                        int* __restrict__ blocksum, int n) {
    __shared__ int s[256];
    int t = threadIdx.x;
    int i = blockIdx.x * 256 + t;
    int v = (i < n) ? indeg[i] : 0;
    s[t] = v;
    __syncthreads();
    for (int d = 1; d < 256; d <<= 1) {
        int u = (t >= d) ? s[t - d] : 0;
        __syncthreads();
        s[t] += u;
        __syncthreads();
    }
    if (i < n) local[i] = s[t] - v; // exclusive within block
    if (t == 255) blocksum[blockIdx.x] = s[255];
}

__global__ void k_scan2(int* __restrict__ blocksum, int nb) {
    __shared__ int s[256];
    int t = threadIdx.x;
    int v = (t < nb) ? blocksum[t] : 0;
    s[t] = v;
    __syncthreads();
    for (int d = 1; d < 256; d <<= 1) {
        int u = (t >= d) ? s[t - d] : 0;
        __syncthreads();
        s[t] += u;
        __syncthreads();
    }
    if (t < nb) blocksum[t] = s[t] - v; // exclusive block offsets
}

__global__ void k_scan3(const int* __restrict__ local, const int* __restrict__ blocksum,
                        const int* __restrict__ indeg, int* __restrict__ off,
                        int* __restrict__ cursor, int n) {
    int i = blockIdx.x * 256 + threadIdx.x;
    if (i < n) {
        int o = local[i] + blocksum[blockIdx.x];
        off[i] = o;
        cursor[i] = o;
        if (i == n - 1) off[n] = o + indeg[i];
    }
}

__global__ void k_fill(const int* __restrict__ src, const int* __restrict__ dst,
                       int* __restrict__ cursor, int* __restrict__ csr, int n) {
    int i = blockIdx.x * blockDim.x + threadIdx.x;
    if (i < n) {
        int p = atomicAdd(&cursor[dst[i]], 1);
        csr[p] = src[i];
    }
}

// ---------------- aggregation: h = x + sum_{incoming} x[src] ----------------

__global__ void k_aggregate(const unsigned short* __restrict__ x, const int* __restrict__ off,
                            const int* __restrict__ csr, unsigned short* __restrict__ h) {
    int wid = (int)((blockIdx.x * blockDim.x + threadIdx.x) >> 6);
    if (wid >= NN) return;
    int lane = threadIdx.x & 63;
    const uint4* xr = (const uint4*)x; // row = 64 uint4
    uint4 v = xr[(size_t)wid * 64 + lane];
    float acc[8];
    {
        unsigned short* p = (unsigned short*)&v;
        for (int i = 0; i < 8; i++) acc[i] = bf2f(p[i]);
    }
    int e0 = off[wid], e1 = off[wid + 1];
    for (int e = e0; e < e1; e++) {
        int u = csr[e];
        uint4 vu = xr[(size_t)u * 64 + lane];
        unsigned short* p = (unsigned short*)&vu;
        for (int i = 0; i < 8; i++) acc[i] += bf2f(p[i]);
    }
    uint4 o;
    unsigned short* po = (unsigned short*)&o;
    for (int i = 0; i < 8; i++) po[i] = f2bf(acc[i]);
    ((uint4*)h)[(size_t)wid * 64 + lane] = o;
}

// ---------------- bf16 MFMA GEMM: C[M,512] = A[M,K] * W^T[512,K] ----------------
// NEW STRUCTURE (barrier-free K-loop):
//  - B-tile (128 cols x full K) resident in LDS, loaded ONCE -> one __syncthreads total.
//  - A streamed global->register per wave (private rows), 1-step-ahead double buffer;
//    compiler emits counted vmcnt waits (no barrier ever drains the pipeline).
//  - BM=256 (4 waves x 64 rows), BN=128. Grid 196x4=784, XCD-chunked N-major swizzle
//    keeps one B-panel hot per XCD L2.

template <int RELU, int NSTEPS>
__global__ __launch_bounds__(256, 1) void k_gemm(const unsigned short* __restrict__ A,
                                                 const unsigned short* __restrict__ WT,
                                                 const float* __restrict__ scale,
                                                 const float* __restrict__ shift,
                                                 unsigned short* __restrict__ out, int M) {
    constexpr int K = NSTEPS * 64;
    __shared__ char lds[NSTEPS * 16 * 1024]; // B chunks: c=(ks*8+nf)*2+kf, 1 KB each
    const int tid = threadIdx.x, w = tid >> 6, lane = tid & 63;
    const int lr = lane & 15, lh = lane >> 4;

    // bijective XCD-chunked swizzle, N-major (same n-tile contiguous per XCD)
    int orig = blockIdx.x;
    int wgid = (orig & 7) * (GEMM_NWG / 8) + (orig >> 3);
    int nt = wgid / MT_TILES;
    int mt = wgid - nt * MT_TILES;
    int tile_m = mt * 256, n0 = nt * 128;

    // per-wave A row pointers (4 m-frags of 16 rows each; this wave owns rows w*64..w*64+63)
    const unsigned short* pA[4];
#pragma unroll
    for (int mf = 0; mf < 4; mf++) {
        int row = tile_m + w * 64 + mf * 16 + lr;
        if (row >= M) row = M - 1;
        pA[mf] = A + (size_t)row * K + lh * 8;
    }

    // issue A step-0 loads (regs), then B staging (LDS), then one barrier
    uint4 a0[8], a1[8]; // [kf*4+mf], two named buffers (static indexing only)
#pragma unroll
    for (int x = 0; x < 8; x++)
        a0[x] = *(const uint4*)(pA[x & 3] + (x >> 2) * 32);

    for (int c = w; c < NSTEPS * 16; c += 4) {
        int kf = c & 1, nf = (c >> 1) & 7, ks = c >> 4;
        async16(WT + (size_t)(n0 + nf * 16 + lr) * K + ks * 64 + kf * 32 + lh * 8,
                lds + c * 1024);
    }
    __syncthreads(); // the only barrier

    f32x4 acc[4][8];
#pragma unroll
    for (int i = 0; i < 4; i++)
#pragma unroll
        for (int j = 0; j < 8; j++) acc[i][j] = f32x4{0.f, 0.f, 0.f, 0.f};

#pragma unroll
    for (int ks = 0; ks < NSTEPS; ks++) {
        if (ks + 1 < NSTEPS) { // prefetch next K-step into the other reg buffer
#pragma unroll
            for (int x = 0; x < 8; x++) {
                uint4 v = *(const uint4*)(pA[x & 3] + (ks + 1) * 64 + (x >> 2) * 32);
                if (ks & 1) a0[x] = v; else a1[x] = v;
            }
        }
#pragma unroll
        for (int kf = 0; kf < 2; kf++) {
            bf16x8 b[8];
#pragma unroll
            for (int nf = 0; nf < 8; nf++)
                b[nf] = *(const bf16x8*)(lds + ((ks * 8 + nf) * 2 + kf) * 1024 + lane * 16);
#pragma unroll
            for (int mf = 0; mf < 4; mf++) {
                uint4 u = (ks & 1) ? a1[kf * 4 + mf] : a0[kf * 4 + mf];
                bf16x8 av = *(bf16x8*)&u;
#pragma unroll
                for (int nf = 0; nf < 8; nf++)
                    acc[mf][nf] = __builtin_amdgcn_mfma_f32_16x16x32_bf16(av, b[nf], acc[mf][nf], 0, 0, 0);
            }
        }
    }

    // epilogue: affine + optional relu, guarded store
#pragma unroll
    for (int mf = 0; mf < 4; mf++)
#pragma unroll
        for (int nf = 0; nf < 8; nf++) {
            int col = n0 + nf * 16 + lr;
            float sc = scale[col], sh = shift[col];
#pragma unroll
            for (int j = 0; j < 4; j++) {
                int row = tile_m + w * 64 + mf * 16 + lh * 4 + j;
                if (row < M) {
                    float y = acc[mf][nf][j] * sc + sh;
                    if (RELU) y = fmaxf(y, 0.f);
                    out[(size_t)row * HID + col] = f2bf(y);
                }
            }
        }
}

// ---------------- pooling + head ----------------

__global__ void k_bounds(const int* __restrict__ batch, int* __restrict__ bounds) {
    int t = threadIdx.x;
    if (t <= NG) {
        int lo = 0, hi = NN;
        while (lo < hi) { int mid = (lo + hi) >> 1; if (batch[mid] < t) lo = mid + 1; else hi = mid; }
        bounds[t] = lo;
    }
}

__global__ void k_pool(const unsigned short* __restrict__ x, const int* __restrict__ bounds,
                       float* __restrict__ pooled) {
    int g = blockIdx.x, s = blockIdx.y, t = threadIdx.x; // 512 thr
    int b0 = bounds[g], b1 = bounds[g + 1];
    int len = b1 - b0;
    int r0 = b0 + (int)((long long)len * s / 8);
    int r1 = b0 + (int)((long long)len * (s + 1) / 8);
    float acc = 0.f;
    for (int r = r0; r < r1; r++) acc += bf2f(x[(size_t)r * HID + t]);
    if (r1 > r0) atomicAdd(&pooled[g * HID + t], acc);
}

__global__ void k_head1(const float* __restrict__ pooled, const int* __restrict__ bounds,
                        const float* __restrict__ lin_w, const float* __restrict__ lin_b,
                        float* __restrict__ gout) {
    int g = blockIdx.x, t = threadIdx.x; // 512
    __shared__ float row[HID];
    int cnt = bounds[g + 1] - bounds[g];
    float invc = 1.f / fmaxf((float)cnt, 1.f);
    row[t] = pooled[g * HID + t] * invc;
    __syncthreads();
    float acc = lin_b[t];
    for (int k = 0; k < HID; k++) acc += row[k] * lin_w[(size_t)k * HID + t];
    gout[g * HID + t] = 0.5f * acc * (1.f + erff(acc * 0.7071067811865475f));
}

__global__ void k_head2(const float* __restrict__ gbuf, const float* __restrict__ clf_w,
                        const float* __restrict__ clf_b, float* __restrict__ out) {
    int g = blockIdx.x, t = threadIdx.x; // 128
    __shared__ float row[HID];
    for (int k = t; k < HID; k += 128) row[k] = gbuf[g * HID + k];
    __syncthreads();
    float acc = clf_b[t];
    for (int k = 0; k < HID; k++) acc += row[k] * clf_w[(size_t)k * COUT + t];
    out[g * COUT + t] = acc;
}

// ---------------- launch ----------------

extern "C" void kernel_launch(void* const* d_in, const int* in_sizes, int n_in,
                              void* d_out, int out_size, void* d_ws, size_t ws_size,
                              hipStream_t stream) {
    const float* x_f32   = (const float*)d_in[0];
    const int*   ei      = (const int*)d_in[1];
    const int*   batch   = (const int*)d_in[2];
    const float* enc_w   = (const float*)d_in[3];
    const float* enc_b   = (const float*)d_in[4];
    const float* conv_w0 = (const float*)d_in[5];
    const float* conv_b0 = (const float*)d_in[6];
    const float* bn0_g   = (const float*)d_in[7];
    const float* bn0_b   = (const float*)d_in[8];
    const float* conv_w1 = (const float*)d_in[9];
    const float* conv_b1 = (const float*)d_in[10];
    const float* bn1_g   = (const float*)d_in[11];
    const float* bn1_b   = (const float*)d_in[12];
    const float* lin_w   = (const float*)d_in[13];
    const float* lin_b   = (const float*)d_in[14];
    const float* clf_w   = (const float*)d_in[15];
    const float* clf_b   = (const float*)d_in[16];
    const int* srcp = ei;
    const int* dstp = ei + NE;

    char* ws = (char*)d_ws;
    size_t o = 0;
    auto alloc = [&](size_t b) { size_t r = o; o += (b + 255) & ~(size_t)255; return r; };
    unsigned short* buf0 = (unsigned short*)(ws + alloc((size_t)NN * HID * 2));
    unsigned short* buf1 = (unsigned short*)(ws + alloc((size_t)NN * HID * 2));
    unsigned short* buf2 = (unsigned short*)(ws + alloc((size_t)NN * HID * 2));
    unsigned short* xbf = buf1; // alias: encoder input dead before buf1's first real use
    unsigned short* encT = (unsigned short*)(ws + alloc((size_t)HID * CIN * 2));
    unsigned short* c0T  = (unsigned short*)(ws + alloc((size_t)2 * HID * HID * 2));
    unsigned short* c1T  = (unsigned short*)(ws + alloc((size_t)2 * HID * HID * 2));
    float* aff_scale = (float*)(ws + alloc(5 * HID * 4));
    float* aff_shift = (float*)(ws + alloc(5 * HID * 4));
    int* indeg  = (int*)(ws + alloc((size_t)NN * 4));
    int* off    = (int*)(ws + alloc((size_t)(NN + 1) * 4));
    int* cursor = (int*)(ws + alloc((size_t)NN * 4));
    int* csr    = (int*)(ws + alloc((size_t)NE * 4));
    int* scan_local = (int*)(ws + alloc((size_t)NN * 4));
    int* scan_bsum  = (int*)(ws + alloc((size_t)256 * 4));
    int* bounds = (int*)(ws + alloc((size_t)(NG + 1) * 4));
    float* pooled = (float*)(ws + alloc((size_t)NG * HID * 4));
    float* gbuf   = (float*)(ws + alloc((size_t)NG * HID * 4));
    (void)ws_size; (void)n_in; (void)in_sizes; (void)out_size;

    hipMemsetAsync(indeg, 0, (size_t)NN * 4, stream);
    hipMemsetAsync(pooled, 0, (size_t)NG * HID * 4, stream);

    // weight prep
    k_f32_to_bf16<<<(NN * CIN / 4 + 255) / 256, 256, 0, stream>>>(x_f32, xbf, NN * CIN / 4);
    k_transpose_cvt<<<dim3(HID / 32, CIN / 32), 256, 0, stream>>>(enc_w, encT, CIN, HID);
    k_transpose_cvt<<<dim3(16, 16), 256, 0, stream>>>(conv_w0, c0T, HID, HID);
    k_transpose_cvt<<<dim3(16, 16), 256, 0, stream>>>(conv_w0 + HID * HID, c0T + HID * HID, HID, HID);
    k_transpose_cvt<<<dim3(16, 16), 256, 0, stream>>>(conv_w1, c1T, HID, HID);
    k_transpose_cvt<<<dim3(16, 16), 256, 0, stream>>>(conv_w1 + HID * HID, c1T + HID * HID, HID, HID);
    k_affine<<<1, 512, 0, stream>>>(enc_b, conv_b0, bn0_g, bn0_b, conv_b1, bn1_g, bn1_b,
                                    aff_scale, aff_shift);

    // CSR (hierarchical scan)
    k_hist<<<(NE + 255) / 256, 256, 0, stream>>>(dstp, indeg, NE);
    k_scan1<<<SCAN_NB, 256, 0, stream>>>(indeg, scan_local, scan_bsum, NN);
    k_scan2<<<1, 256, 0, stream>>>(scan_bsum, SCAN_NB);
    k_scan3<<<SCAN_NB, 256, 0, stream>>>(scan_local, scan_bsum, indeg, off, cursor, NN);
    k_fill<<<(NE + 255) / 256, 256, 0, stream>>>(srcp, dstp, cursor, csr, NE);
    k_bounds<<<1, 128, 0, stream>>>(batch, bounds);

    // encoder (K=256 -> NSTEPS=4)
    k_gemm<0, CIN / 64><<<GEMM_NWG, 256, 0, stream>>>(xbf, encT, aff_scale, aff_shift, buf0, NN);

    // GIN layers (K=512 -> NSTEPS=8)
    for (int l = 0; l < 2; l++) {
        k_aggregate<<<(NN * 64) / 256, 256, 0, stream>>>(buf0, off, csr, buf1);
        k_gemm<1, HID / 64><<<GEMM_NWG, 256, 0, stream>>>(buf1, c0T + (size_t)l * HID * HID,
                                                          aff_scale + (1 + 2 * l) * HID,
                                                          aff_shift + (1 + 2 * l) * HID,
                                                          buf2, NN);
        if (l == 0)
            k_gemm<1, HID / 64><<<GEMM_NWG, 256, 0, stream>>>(buf2, c1T + (size_t)l * HID * HID,
                                                              aff_scale + (2 + 2 * l) * HID,
                                                              aff_shift + (2 + 2 * l) * HID,
                                                              buf0, NN);
        else
            k_gemm<0, HID / 64><<<GEMM_NWG, 256, 0, stream>>>(buf2, c1T + (size_t)l * HID * HID,
                                                              aff_scale + (2 + 2 * l) * HID,
                                                              aff_shift + (2 + 2 * l) * HID,
                                                              buf0, NN);
    }

    // pool + head
    k_pool<<<dim3(NG, 8), 512, 0, stream>>>(buf0, bounds, pooled);
    k_head1<<<NG, 512, 0, stream>>>(pooled, bounds, lin_w, lin_b, gbuf);
    k_head2<<<NG, 128, 0, stream>>>(gbuf, clf_w, clf_b, (float*)d_out);
}

// Round 5
// 726.942 us; speedup vs baseline: 1.0453x; 1.0453x over previous
//
#include <hip/hip_runtime.h>
#include <hip/hip_bf16.h>
#include <stdint.h>

#define NN 50000
#define NE 400000
#define CIN 256
#define HID 512
#define COUT 128
#define NG 64
#define SCAN_NB ((NN + 255) / 256)   // 196
#define MT_TILES ((NN + 255) / 256)  // 196 M-tiles of 256 rows
#define GEMM_NWG (MT_TILES * 4)      // 784 = 8 * 98

typedef short bf16x8 __attribute__((ext_vector_type(8)));
typedef float f32x4 __attribute__((ext_vector_type(4)));

__device__ inline float bf2f(unsigned short u) {
    union { unsigned int i; float f; } v; v.i = ((unsigned int)u) << 16; return v.f;
}
__device__ inline unsigned short f2bf(float f) {
    union { float f; unsigned int u; } v; v.f = f;
    unsigned int r = v.u + 0x7fffu + ((v.u >> 16) & 1u);
    return (unsigned short)(r >> 16);
}

__device__ inline void async16(const void* g, void* l) {
    __builtin_amdgcn_global_load_lds((const __attribute__((address_space(1))) void*)g,
                                     (__attribute__((address_space(3))) void*)l, 16, 0, 0);
}

// ---------------- small prep kernels ----------------

__global__ void k_f32_to_bf16(const float* __restrict__ in, unsigned short* __restrict__ out, int n4) {
    int i = blockIdx.x * blockDim.x + threadIdx.x;
    if (i < n4) {
        float4 v = ((const float4*)in)[i];
        ushort4 o;
        o.x = f2bf(v.x); o.y = f2bf(v.y); o.z = f2bf(v.z); o.w = f2bf(v.w);
        ((ushort4*)out)[i] = o;
    }
}

// in: [K][N] f32 row-major -> out: [N][K] bf16
__global__ void k_transpose_cvt(const float* __restrict__ in, unsigned short* __restrict__ out, int K, int N) {
    __shared__ float tile[32][33];
    int bx = blockIdx.x * 32, by = blockIdx.y * 32;
    int tx = threadIdx.x & 31, ty = threadIdx.x >> 5; // 256 thr: ty 0..7
    for (int i = 0; i < 32; i += 8)
        tile[ty + i][tx] = in[(size_t)(by + ty + i) * N + bx + tx];
    __syncthreads();
    for (int i = 0; i < 32; i += 8)
        out[(size_t)(bx + ty + i) * K + by + tx] = f2bf(tile[tx][ty + i]);
}

// per-column fused scale/shift for the 5 GEMM epilogues
__global__ void k_affine(const float* __restrict__ enc_b,
                         const float* __restrict__ cb0, const float* __restrict__ bg0, const float* __restrict__ bb0,
                         const float* __restrict__ cb1, const float* __restrict__ bg1, const float* __restrict__ bb1,
                         float* __restrict__ scale, float* __restrict__ shift) {
    int c = threadIdx.x; // 512
    const float inv = 0.9999950000374997f; // 1/sqrt(1+1e-5)
    scale[c] = 1.f; shift[c] = enc_b[c];
    for (int l = 0; l < 2; l++) {
        float s0 = bg0[l * HID + c] * inv;
        scale[(1 + 2 * l) * HID + c] = s0;
        shift[(1 + 2 * l) * HID + c] = cb0[l * HID + c] * s0 + bb0[l * HID + c];
        float s1 = bg1[l * HID + c] * inv;
        scale[(2 + 2 * l) * HID + c] = s1;
        shift[(2 + 2 * l) * HID + c] = cb1[l * HID + c] * s1 + bb1[l * HID + c];
    }
}

// ---------------- CSR build ----------------

__global__ void k_hist(const int* __restrict__ dst, int* __restrict__ indeg, int n) {
    int i = blockIdx.x * blockDim.x + threadIdx.x;
    if (i < n) atomicAdd(&indeg[dst[i]], 1);
}

__global__ void k_scan1(const int* __restrict__ indeg, int* __restrict__ local,
                        int* __restrict__ blocksum, int n) {
    __shared__ int s[256];
    int t = threadIdx.x;
    int i = blockIdx.x * 256 + t;
    int v = (i < n) ? indeg[i] : 0;
    s[t] = v;
    __syncthreads();
    for (int d = 1; d < 256; d <<= 1) {
        int u = (t >= d) ? s[t - d] : 0;
        __syncthreads();
        s[t] += u;
        __syncthreads();
    }
    if (i < n) local[i] = s[t] - v; // exclusive within block
    if (t == 255) blocksum[blockIdx.x] = s[255];
}

__global__ void k_scan2(int* __restrict__ blocksum, int nb) {
    __shared__ int s[256];
    int t = threadIdx.x;
    int v = (t < nb) ? blocksum[t] : 0;
    s[t] = v;
    __syncthreads();
    for (int d = 1; d < 256; d <<= 1) {
        int u = (t >= d) ? s[t - d] : 0;
        __syncthreads();
        s[t] += u;
        __syncthreads();
    }
    if (t < nb) blocksum[t] = s[t] - v; // exclusive block offsets
}

__global__ void k_scan3(const int* __restrict__ local, const int* __restrict__ blocksum,
                        const int* __restrict__ indeg, int* __restrict__ off,
                        int* __restrict__ cursor, int n) {
    int i = blockIdx.x * 256 + threadIdx.x;
    if (i < n) {
        int o = local[i] + blocksum[blockIdx.x];
        off[i] = o;
        cursor[i] = o;
        if (i == n - 1) off[n] = o + indeg[i];
    }
}

__global__ void k_fill(const int* __restrict__ src, const int* __restrict__ dst,
                       int* __restrict__ cursor, int* __restrict__ csr, int n) {
    int i = blockIdx.x * blockDim.x + threadIdx.x;
    if (i < n) {
        int p = atomicAdd(&cursor[dst[i]], 1);
        csr[p] = src[i];
    }
}

// ---------------- aggregation: h = x + sum_{incoming} x[src] ----------------
// one wave per node; 4-way edge unroll for memory-level parallelism

__global__ void k_aggregate(const unsigned short* __restrict__ x, const int* __restrict__ off,
                            const int* __restrict__ csr, unsigned short* __restrict__ h) {
    int wid = (int)((blockIdx.x * blockDim.x + threadIdx.x) >> 6);
    if (wid >= NN) return;
    int lane = threadIdx.x & 63;
    const uint4* xr = (const uint4*)x; // row = 64 uint4
    uint4 v = xr[(size_t)wid * 64 + lane];
    float acc[8];
    {
        unsigned short* p = (unsigned short*)&v;
        for (int i = 0; i < 8; i++) acc[i] = bf2f(p[i]);
    }
    int e0 = off[wid], e1 = off[wid + 1];
    int e = e0;
    for (; e + 3 < e1; e += 4) {
        int u0 = csr[e], u1 = csr[e + 1], u2 = csr[e + 2], u3 = csr[e + 3];
        uint4 v0 = xr[(size_t)u0 * 64 + lane];
        uint4 v1 = xr[(size_t)u1 * 64 + lane];
        uint4 v2 = xr[(size_t)u2 * 64 + lane];
        uint4 v3 = xr[(size_t)u3 * 64 + lane];
        unsigned short* p0 = (unsigned short*)&v0;
        unsigned short* p1 = (unsigned short*)&v1;
        unsigned short* p2 = (unsigned short*)&v2;
        unsigned short* p3 = (unsigned short*)&v3;
#pragma unroll
        for (int i = 0; i < 8; i++)
            acc[i] += (bf2f(p0[i]) + bf2f(p1[i])) + (bf2f(p2[i]) + bf2f(p3[i]));
    }
    for (; e < e1; e++) {
        int u = csr[e];
        uint4 vu = xr[(size_t)u * 64 + lane];
        unsigned short* p = (unsigned short*)&vu;
#pragma unroll
        for (int i = 0; i < 8; i++) acc[i] += bf2f(p[i]);
    }
    uint4 o;
    unsigned short* po = (unsigned short*)&o;
    for (int i = 0; i < 8; i++) po[i] = f2bf(acc[i]);
    ((uint4*)h)[(size_t)wid * 64 + lane] = o;
}

// ---------------- bf16 MFMA GEMM: C[M,512] = A[M,K] * W^T[512,K] ----------------
// Barrier-free K-loop, done right this time:
//  - B-tile (128 cols x full K) resident in LDS, loaded ONCE (one __syncthreads total).
//  - 512 thr = 8 waves (2/SIMD); wave w owns a 64x64 output quadrant (wr=w&3, wc=w>>2)
//    -> per-wave LDS reads 8 KB/K-step, per-SIMD MFMA 1240 cyc/K-step (compute-dominant).
//  - A streamed global->register, 1-step-ahead named double buffer, static indexing.
//  - M-major XCD-chunked swizzle (R2's winner): 4 n-tiles of one A-panel adjacent on one XCD.

template <int RELU, int NSTEPS>
__global__ __launch_bounds__(512, 2) void k_gemm(const unsigned short* __restrict__ A,
                                                 const unsigned short* __restrict__ WT,
                                                 const float* __restrict__ scale,
                                                 const float* __restrict__ shift,
                                                 unsigned short* __restrict__ out, int M) {
    constexpr int K = NSTEPS * 64;
    __shared__ char lds[NSTEPS * 16 * 1024]; // B chunks: c=(ks*8+nfg)*2+kf, 1 KB each
    const int tid = threadIdx.x, w = tid >> 6, lane = tid & 63;
    const int wr = w & 3, wc = w >> 2;
    const int lr = lane & 15, lh = lane >> 4;

    // M-major bijective XCD-chunked swizzle (784 = 8 * 98)
    int orig = blockIdx.x;
    int wgid = (orig & 7) * (GEMM_NWG / 8) + (orig >> 3);
    int tile_m = (wgid >> 2) * 256;
    int n0 = (wgid & 3) * 128;

    // per-wave A row pointers: wave rows = tile_m + wr*64 + mf*16 + lr, mf in [0,4)
    const unsigned short* pA[4];
#pragma unroll
    for (int mf = 0; mf < 4; mf++) {
        int row = tile_m + wr * 64 + mf * 16 + lr;
        if (row >= M) row = M - 1;
        pA[mf] = A + (size_t)row * K + lh * 8;
    }

    // issue A step-0 loads (regs), then B staging (LDS), then the only barrier
    uint4 a0[8], a1[8]; // x = kf*4 + mf
#pragma unroll
    for (int x = 0; x < 8; x++)
        a0[x] = *(const uint4*)(pA[x & 3] + (x >> 2) * 32);

    for (int c = w; c < NSTEPS * 16; c += 8) {
        int kf = c & 1, nfg = (c >> 1) & 7, ks = c >> 4;
        async16(WT + (size_t)(n0 + nfg * 16 + lr) * K + ks * 64 + kf * 32 + lh * 8,
                lds + c * 1024);
    }
    __syncthreads(); // the only barrier

    f32x4 acc[4][4];
#pragma unroll
    for (int i = 0; i < 4; i++)
#pragma unroll
        for (int j = 0; j < 4; j++) acc[i][j] = f32x4{0.f, 0.f, 0.f, 0.f};

    const int wc4 = wc * 4;
#pragma unroll
    for (int ks = 0; ks < NSTEPS; ks++) {
        const bool odd = (ks & 1) != 0;
        if (ks + 1 < NSTEPS) { // prefetch next K-step into the other reg buffer
#pragma unroll
            for (int x = 0; x < 8; x++) {
                uint4 v = *(const uint4*)(pA[x & 3] + (ks + 1) * 64 + (x >> 2) * 32);
                if (odd) a0[x] = v; else a1[x] = v;
            }
        }
#pragma unroll
        for (int kf = 0; kf < 2; kf++) {
            bf16x8 b[4];
#pragma unroll
            for (int nf = 0; nf < 4; nf++)
                b[nf] = *(const bf16x8*)(lds + ((ks * 8 + wc4 + nf) * 2 + kf) * 1024 + lane * 16);
#pragma unroll
            for (int mf = 0; mf < 4; mf++) {
                uint4 u = odd ? a1[kf * 4 + mf] : a0[kf * 4 + mf];
                bf16x8 av = *(bf16x8*)&u;
#pragma unroll
                for (int nf = 0; nf < 4; nf++)
                    acc[mf][nf] = __builtin_amdgcn_mfma_f32_16x16x32_bf16(av, b[nf], acc[mf][nf], 0, 0, 0);
            }
        }
    }

    // epilogue: affine + optional relu, guarded store
#pragma unroll
    for (int mf = 0; mf < 4; mf++)
#pragma unroll
        for (int nf = 0; nf < 4; nf++) {
            int col = n0 + wc * 64 + nf * 16 + lr;
            float sc = scale[col], sh = shift[col];
#pragma unroll
            for (int j = 0; j < 4; j++) {
                int row = tile_m + wr * 64 + mf * 16 + lh * 4 + j;
                if (row < M) {
                    float y = acc[mf][nf][j] * sc + sh;
                    if (RELU) y = fmaxf(y, 0.f);
                    out[(size_t)row * HID + col] = f2bf(y);
                }
            }
        }
}

// ---------------- pooling + head ----------------

__global__ void k_bounds(const int* __restrict__ batch, int* __restrict__ bounds) {
    int t = threadIdx.x;
    if (t <= NG) {
        int lo = 0, hi = NN;
        while (lo < hi) { int mid = (lo + hi) >> 1; if (batch[mid] < t) lo = mid + 1; else hi = mid; }
        bounds[t] = lo;
    }
}

__global__ void k_pool(const unsigned short* __restrict__ x, const int* __restrict__ bounds,
                       float* __restrict__ pooled) {
    int g = blockIdx.x, s = blockIdx.y, t = threadIdx.x; // 512 thr
    int b0 = bounds[g], b1 = bounds[g + 1];
    int len = b1 - b0;
    int r0 = b0 + (int)((long long)len * s / 8);
    int r1 = b0 + (int)((long long)len * (s + 1) / 8);
    float acc = 0.f;
    for (int r = r0; r < r1; r++) acc += bf2f(x[(size_t)r * HID + t]);
    if (r1 > r0) atomicAdd(&pooled[g * HID + t], acc);
}

__global__ void k_head1(const float* __restrict__ pooled, const int* __restrict__ bounds,
                        const float* __restrict__ lin_w, const float* __restrict__ lin_b,
                        float* __restrict__ gout) {
    int g = blockIdx.x, t = threadIdx.x; // 512
    __shared__ float row[HID];
    int cnt = bounds[g + 1] - bounds[g];
    float invc = 1.f / fmaxf((float)cnt, 1.f);
    row[t] = pooled[g * HID + t] * invc;
    __syncthreads();
    float acc = lin_b[t];
    for (int k = 0; k < HID; k++) acc += row[k] * lin_w[(size_t)k * HID + t];
    gout[g * HID + t] = 0.5f * acc * (1.f + erff(acc * 0.7071067811865475f));
}

__global__ void k_head2(const float* __restrict__ gbuf, const float* __restrict__ clf_w,
                        const float* __restrict__ clf_b, float* __restrict__ out) {
    int g = blockIdx.x, t = threadIdx.x; // 128
    __shared__ float row[HID];
    for (int k = t; k < HID; k += 128) row[k] = gbuf[g * HID + k];
    __syncthreads();
    float acc = clf_b[t];
    for (int k = 0; k < HID; k++) acc += row[k] * clf_w[(size_t)k * COUT + t];
    out[g * COUT + t] = acc;
}

// ---------------- launch ----------------

extern "C" void kernel_launch(void* const* d_in, const int* in_sizes, int n_in,
                              void* d_out, int out_size, void* d_ws, size_t ws_size,
                              hipStream_t stream) {
    const float* x_f32   = (const float*)d_in[0];
    const int*   ei      = (const int*)d_in[1];
    const int*   batch   = (const int*)d_in[2];
    const float* enc_w   = (const float*)d_in[3];
    const float* enc_b   = (const float*)d_in[4];
    const float* conv_w0 = (const float*)d_in[5];
    const float* conv_b0 = (const float*)d_in[6];
    const float* bn0_g   = (const float*)d_in[7];
    const float* bn0_b   = (const float*)d_in[8];
    const float* conv_w1 = (const float*)d_in[9];
    const float* conv_b1 = (const float*)d_in[10];
    const float* bn1_g   = (const float*)d_in[11];
    const float* bn1_b   = (const float*)d_in[12];
    const float* lin_w   = (const float*)d_in[13];
    const float* lin_b   = (const float*)d_in[14];
    const float* clf_w   = (const float*)d_in[15];
    const float* clf_b   = (const float*)d_in[16];
    const int* srcp = ei;
    const int* dstp = ei + NE;

    char* ws = (char*)d_ws;
    size_t o = 0;
    auto alloc = [&](size_t b) { size_t r = o; o += (b + 255) & ~(size_t)255; return r; };
    unsigned short* buf0 = (unsigned short*)(ws + alloc((size_t)NN * HID * 2));
    unsigned short* buf1 = (unsigned short*)(ws + alloc((size_t)NN * HID * 2));
    unsigned short* buf2 = (unsigned short*)(ws + alloc((size_t)NN * HID * 2));
    unsigned short* xbf = buf1; // alias: encoder input dead before buf1's first real use
    unsigned short* encT = (unsigned short*)(ws + alloc((size_t)HID * CIN * 2));
    unsigned short* c0T  = (unsigned short*)(ws + alloc((size_t)2 * HID * HID * 2));
    unsigned short* c1T  = (unsigned short*)(ws + alloc((size_t)2 * HID * HID * 2));
    float* aff_scale = (float*)(ws + alloc(5 * HID * 4));
    float* aff_shift = (float*)(ws + alloc(5 * HID * 4));
    int* indeg  = (int*)(ws + alloc((size_t)NN * 4));
    int* off    = (int*)(ws + alloc((size_t)(NN + 1) * 4));
    int* cursor = (int*)(ws + alloc((size_t)NN * 4));
    int* csr    = (int*)(ws + alloc((size_t)NE * 4));
    int* scan_local = (int*)(ws + alloc((size_t)NN * 4));
    int* scan_bsum  = (int*)(ws + alloc((size_t)256 * 4));
    int* bounds = (int*)(ws + alloc((size_t)(NG + 1) * 4));
    float* pooled = (float*)(ws + alloc((size_t)NG * HID * 4));
    float* gbuf   = (float*)(ws + alloc((size_t)NG * HID * 4));
    (void)ws_size; (void)n_in; (void)in_sizes; (void)out_size;

    hipMemsetAsync(indeg, 0, (size_t)NN * 4, stream);
    hipMemsetAsync(pooled, 0, (size_t)NG * HID * 4, stream);

    // weight prep
    k_f32_to_bf16<<<(NN * CIN / 4 + 255) / 256, 256, 0, stream>>>(x_f32, xbf, NN * CIN / 4);
    k_transpose_cvt<<<dim3(HID / 32, CIN / 32), 256, 0, stream>>>(enc_w, encT, CIN, HID);
    k_transpose_cvt<<<dim3(16, 16), 256, 0, stream>>>(conv_w0, c0T, HID, HID);
    k_transpose_cvt<<<dim3(16, 16), 256, 0, stream>>>(conv_w0 + HID * HID, c0T + HID * HID, HID, HID);
    k_transpose_cvt<<<dim3(16, 16), 256, 0, stream>>>(conv_w1, c1T, HID, HID);
    k_transpose_cvt<<<dim3(16, 16), 256, 0, stream>>>(conv_w1 + HID * HID, c1T + HID * HID, HID, HID);
    k_affine<<<1, 512, 0, stream>>>(enc_b, conv_b0, bn0_g, bn0_b, conv_b1, bn1_g, bn1_b,
                                    aff_scale, aff_shift);

    // CSR (hierarchical scan)
    k_hist<<<(NE + 255) / 256, 256, 0, stream>>>(dstp, indeg, NE);
    k_scan1<<<SCAN_NB, 256, 0, stream>>>(indeg, scan_local, scan_bsum, NN);
    k_scan2<<<1, 256, 0, stream>>>(scan_bsum, SCAN_NB);
    k_scan3<<<SCAN_NB, 256, 0, stream>>>(scan_local, scan_bsum, indeg, off, cursor, NN);
    k_fill<<<(NE + 255) / 256, 256, 0, stream>>>(srcp, dstp, cursor, csr, NE);
    k_bounds<<<1, 128, 0, stream>>>(batch, bounds);

    // encoder (K=256 -> NSTEPS=4)
    k_gemm<0, CIN / 64><<<GEMM_NWG, 512, 0, stream>>>(xbf, encT, aff_scale, aff_shift, buf0, NN);

    // GIN layers (K=512 -> NSTEPS=8)
    for (int l = 0; l < 2; l++) {
        k_aggregate<<<(NN * 64) / 256, 256, 0, stream>>>(buf0, off, csr, buf1);
        k_gemm<1, HID / 64><<<GEMM_NWG, 512, 0, stream>>>(buf1, c0T + (size_t)l * HID * HID,
                                                          aff_scale + (1 + 2 * l) * HID,
                                                          aff_shift + (1 + 2 * l) * HID,
                                                          buf2, NN);
        if (l == 0)
            k_gemm<1, HID / 64><<<GEMM_NWG, 512, 0, stream>>>(buf2, c1T + (size_t)l * HID * HID,
                                                              aff_scale + (2 + 2 * l) * HID,
                                                              aff_shift + (2 + 2 * l) * HID,
                                                              buf0, NN);
        else
            k_gemm<0, HID / 64><<<GEMM_NWG, 512, 0, stream>>>(buf2, c1T + (size_t)l * HID * HID,
                                                              aff_scale + (2 + 2 * l) * HID,
                                                              aff_shift + (2 + 2 * l) * HID,
                                                              buf0, NN);
    }

    // pool + head
    k_pool<<<dim3(NG, 8), 512, 0, stream>>>(buf0, bounds, pooled);
    k_head1<<<NG, 512, 0, stream>>>(pooled, bounds, lin_w, lin_b, gbuf);
    k_head2<<<NG, 128, 0, stream>>>(gbuf, clf_w, clf_b, (float*)d_out);
}

// Round 6
// 635.713 us; speedup vs baseline: 1.1953x; 1.1435x over previous
//
#include <hip/hip_runtime.h>
#include <hip/hip_bf16.h>
#include <stdint.h>

#define NN 50000
#define NE 400000
#define CIN 256
#define HID 512
#define COUT 128
#define NG 64
#define SCAN_NB ((NN + 255) / 256)          // 196
#define GEMM_NWG (((NN + 127) / 128) * 4)   // 1564 (q=195, r=4 for bijective XCD swizzle)

typedef short bf16x8 __attribute__((ext_vector_type(8)));
typedef float f32x4 __attribute__((ext_vector_type(4)));

__device__ inline float bf2f(unsigned short u) {
    union { unsigned int i; float f; } v; v.i = ((unsigned int)u) << 16; return v.f;
}
__device__ inline unsigned short f2bf(float f) {
    union { float f; unsigned int u; } v; v.f = f;
    unsigned int r = v.u + 0x7fffu + ((v.u >> 16) & 1u);
    return (unsigned short)(r >> 16);
}

__device__ inline void async16(const void* g, void* l) {
    __builtin_amdgcn_global_load_lds((const __attribute__((address_space(1))) void*)g,
                                     (__attribute__((address_space(3))) void*)l, 16, 0, 0);
}

// ---------------- small prep kernels ----------------

__global__ void k_f32_to_bf16(const float* __restrict__ in, unsigned short* __restrict__ out, int n4) {
    int i = blockIdx.x * blockDim.x + threadIdx.x;
    if (i < n4) {
        float4 v = ((const float4*)in)[i];
        ushort4 o;
        o.x = f2bf(v.x); o.y = f2bf(v.y); o.z = f2bf(v.z); o.w = f2bf(v.w);
        ((ushort4*)out)[i] = o;
    }
}

// in: [K][N] f32 row-major -> out: [N][K] bf16
__global__ void k_transpose_cvt(const float* __restrict__ in, unsigned short* __restrict__ out, int K, int N) {
    __shared__ float tile[32][33];
    int bx = blockIdx.x * 32, by = blockIdx.y * 32;
    int tx = threadIdx.x & 31, ty = threadIdx.x >> 5; // 256 thr: ty 0..7
    for (int i = 0; i < 32; i += 8)
        tile[ty + i][tx] = in[(size_t)(by + ty + i) * N + bx + tx];
    __syncthreads();
    for (int i = 0; i < 32; i += 8)
        out[(size_t)(bx + ty + i) * K + by + tx] = f2bf(tile[tx][ty + i]);
}

// per-column fused scale/shift for the 5 GEMM epilogues
__global__ void k_affine(const float* __restrict__ enc_b,
                         const float* __restrict__ cb0, const float* __restrict__ bg0, const float* __restrict__ bb0,
                         const float* __restrict__ cb1, const float* __restrict__ bg1, const float* __restrict__ bb1,
                         float* __restrict__ scale, float* __restrict__ shift) {
    int c = threadIdx.x; // 512
    const float inv = 0.9999950000374997f; // 1/sqrt(1+1e-5)
    scale[c] = 1.f; shift[c] = enc_b[c];
    for (int l = 0; l < 2; l++) {
        float s0 = bg0[l * HID + c] * inv;
        scale[(1 + 2 * l) * HID + c] = s0;
        shift[(1 + 2 * l) * HID + c] = cb0[l * HID + c] * s0 + bb0[l * HID + c];
        float s1 = bg1[l * HID + c] * inv;
        scale[(2 + 2 * l) * HID + c] = s1;
        shift[(2 + 2 * l) * HID + c] = cb1[l * HID + c] * s1 + bb1[l * HID + c];
    }
}

// ---------------- CSR build ----------------

__global__ void k_hist(const int* __restrict__ dst, int* __restrict__ indeg, int n) {
    int i = blockIdx.x * blockDim.x + threadIdx.x;
    if (i < n) atomicAdd(&indeg[dst[i]], 1);
}

__global__ void k_scan1(const int* __restrict__ indeg, int* __restrict__ local,
                        int* __restrict__ blocksum, int n) {
    __shared__ int s[256];
    int t = threadIdx.x;
    int i = blockIdx.x * 256 + t;
    int v = (i < n) ? indeg[i] : 0;
    s[t] = v;
    __syncthreads();
    for (int d = 1; d < 256; d <<= 1) {
        int u = (t >= d) ? s[t - d] : 0;
        __syncthreads();
        s[t] += u;
        __syncthreads();
    }
    if (i < n) local[i] = s[t] - v; // exclusive within block
    if (t == 255) blocksum[blockIdx.x] = s[255];
}

__global__ void k_scan2(int* __restrict__ blocksum, int nb) {
    __shared__ int s[256];
    int t = threadIdx.x;
    int v = (t < nb) ? blocksum[t] : 0;
    s[t] = v;
    __syncthreads();
    for (int d = 1; d < 256; d <<= 1) {
        int u = (t >= d) ? s[t - d] : 0;
        __syncthreads();
        s[t] += u;
        __syncthreads();
    }
    if (t < nb) blocksum[t] = s[t] - v; // exclusive block offsets
}

__global__ void k_scan3(const int* __restrict__ local, const int* __restrict__ blocksum,
                        const int* __restrict__ indeg, int* __restrict__ off,
                        int* __restrict__ cursor, int n) {
    int i = blockIdx.x * 256 + threadIdx.x;
    if (i < n) {
        int o = local[i] + blocksum[blockIdx.x];
        off[i] = o;
        cursor[i] = o;
        if (i == n - 1) off[n] = o + indeg[i];
    }
}

__global__ void k_fill(const int* __restrict__ src, const int* __restrict__ dst,
                       int* __restrict__ cursor, int* __restrict__ csr, int n) {
    int i = blockIdx.x * blockDim.x + threadIdx.x;
    if (i < n) {
        int p = atomicAdd(&cursor[dst[i]], 1);
        csr[p] = src[i];
    }
}

// ---------------- aggregation: h = x + sum_{incoming} x[src] ----------------
// one wave per node; 4-way edge unroll for memory-level parallelism

__global__ void k_aggregate(const unsigned short* __restrict__ x, const int* __restrict__ off,
                            const int* __restrict__ csr, unsigned short* __restrict__ h) {
    int wid = (int)((blockIdx.x * blockDim.x + threadIdx.x) >> 6);
    if (wid >= NN) return;
    int lane = threadIdx.x & 63;
    const uint4* xr = (const uint4*)x; // row = 64 uint4
    uint4 v = xr[(size_t)wid * 64 + lane];
    float acc[8];
    {
        unsigned short* p = (unsigned short*)&v;
        for (int i = 0; i < 8; i++) acc[i] = bf2f(p[i]);
    }
    int e0 = off[wid], e1 = off[wid + 1];
    int e = e0;
    for (; e + 3 < e1; e += 4) {
        int u0 = csr[e], u1 = csr[e + 1], u2 = csr[e + 2], u3 = csr[e + 3];
        uint4 v0 = xr[(size_t)u0 * 64 + lane];
        uint4 v1 = xr[(size_t)u1 * 64 + lane];
        uint4 v2 = xr[(size_t)u2 * 64 + lane];
        uint4 v3 = xr[(size_t)u3 * 64 + lane];
        unsigned short* p0 = (unsigned short*)&v0;
        unsigned short* p1 = (unsigned short*)&v1;
        unsigned short* p2 = (unsigned short*)&v2;
        unsigned short* p3 = (unsigned short*)&v3;
#pragma unroll
        for (int i = 0; i < 8; i++)
            acc[i] += (bf2f(p0[i]) + bf2f(p1[i])) + (bf2f(p2[i]) + bf2f(p3[i]));
    }
    for (; e < e1; e++) {
        int u = csr[e];
        uint4 vu = xr[(size_t)u * 64 + lane];
        unsigned short* p = (unsigned short*)&vu;
#pragma unroll
        for (int i = 0; i < 8; i++) acc[i] += bf2f(p[i]);
    }
    uint4 o;
    unsigned short* po = (unsigned short*)&o;
    for (int i = 0; i < 8; i++) po[i] = f2bf(acc[i]);
    ((uint4*)h)[(size_t)wid * 64 + lane] = o;
}

// ---------------- bf16 MFMA GEMM: C[M,512] = A[M,K] * W^T[512,K] ----------------
// R3's 2-phase dbuf structure (best measured) + TRANSPOSED-OUTPUT epilogue:
// mfma(b, a, acc) -> lane&15 = M-row, (lane>>4)*4+j = 4 CONTIGUOUS N-cols
// -> one packed 8B ushort4 store per fragment (16 stores/thread, was 64 scalar)
// and float4 scale/shift loads (8/thread, was 32 scalar). Epilogue was the
// K-independent fixed cost dominating all previous rounds.

template <int RELU>
__global__ __launch_bounds__(256) void k_gemm(const unsigned short* __restrict__ A,
                                              const unsigned short* __restrict__ WT,
                                              const float* __restrict__ scale,
                                              const float* __restrict__ shift,
                                              unsigned short* __restrict__ out,
                                              int M, int K, int q, int r) {
    __shared__ uint4 lds4[4096]; // 64 KB: two buffers of (16 KB A + 16 KB B)
    char* lds = (char*)lds4;
    int tid = threadIdx.x, w = tid >> 6, lane = tid & 63;
    int wr = w >> 1, wc = w & 1;
    int lr = lane & 15, lh = lane >> 4;

    // bijective XCD-chunked swizzle (m204), M-major: 4 n-tiles of one A-panel adjacent per XCD
    int orig = blockIdx.x;
    int xcd = orig & 7, idx = orig >> 3;
    int wgid = (xcd < r ? xcd * (q + 1) : r * (q + 1) + (xcd - r) * q) + idx;
    int tile_m = (wgid >> 2) * 128;
    int n0 = (wgid & 3) * 128;

    // hoisted per-thread staging addresses: 4 A-chunks + 4 B-chunks per thread
    const unsigned short* gA[4];
    const unsigned short* gB[4];
    int ldsoff[4];
#pragma unroll
    for (int ci = 0; ci < 4; ci++) {
        int c = w * 4 + ci;
        int f = c >> 1, kf = c & 1;
        int kcol = kf * 32 + lh * 8;
        int row = tile_m + f * 16 + lr;
        if (row >= M) row = M - 1;
        gA[ci] = A + (size_t)row * K + kcol;
        int nrow = n0 + f * 16 + lr;
        gB[ci] = WT + (size_t)nrow * K + kcol;
        ldsoff[ci] = c * 1024;
    }

    f32x4 acc[4][4];
#pragma unroll
    for (int i = 0; i < 4; i++)
#pragma unroll
        for (int j = 0; j < 4; j++) acc[i][j] = f32x4{0.f, 0.f, 0.f, 0.f};

    int nsteps = K >> 6;
    // prologue: stage step 0 into buffer 0
#pragma unroll
    for (int ci = 0; ci < 4; ci++) {
        async16(gA[ci], lds + ldsoff[ci]);
        async16(gB[ci], lds + 16384 + ldsoff[ci]);
    }
    __syncthreads();

    for (int ks = 0; ks < nsteps; ks++) {
        int cur = (ks & 1) << 15;
        if (ks + 1 < nsteps) { // issue next-tile loads into the other buffer FIRST
            int nxt = cur ^ 32768;
            int ko = (ks + 1) << 6;
#pragma unroll
            for (int ci = 0; ci < 4; ci++) {
                async16(gA[ci] + ko, lds + nxt + ldsoff[ci]);
                async16(gB[ci] + ko, lds + nxt + 16384 + ldsoff[ci]);
            }
        }
#pragma unroll
        for (int kf = 0; kf < 2; kf++) {
            bf16x8 a[4], b[4];
#pragma unroll
            for (int mf = 0; mf < 4; mf++)
                a[mf] = *(const bf16x8*)(lds + cur + ((wr * 4 + mf) * 2 + kf) * 1024 + lane * 16);
#pragma unroll
            for (int nf = 0; nf < 4; nf++)
                b[nf] = *(const bf16x8*)(lds + cur + 16384 + ((wc * 4 + nf) * 2 + kf) * 1024 + lane * 16);
#pragma unroll
            for (int mf = 0; mf < 4; mf++)
#pragma unroll
                for (int nf = 0; nf < 4; nf++)
                    acc[mf][nf] = __builtin_amdgcn_mfma_f32_16x16x32_bf16(b[nf], a[mf], acc[mf][nf], 0, 0, 0);
        }
        __syncthreads(); // drains prefetch (vmcnt) + protects cur buffer reuse
    }

    // epilogue (transposed acc): row = M-index from lr, 4 contiguous cols from lh*4+j
#pragma unroll
    for (int nf = 0; nf < 4; nf++) {
        int col = n0 + wc * 64 + nf * 16 + lh * 4;
        float4 sc = *(const float4*)&scale[col];
        float4 sh = *(const float4*)&shift[col];
#pragma unroll
        for (int mf = 0; mf < 4; mf++) {
            int row = tile_m + wr * 64 + mf * 16 + lr;
            if (row < M) {
                float y0 = acc[mf][nf][0] * sc.x + sh.x;
                float y1 = acc[mf][nf][1] * sc.y + sh.y;
                float y2 = acc[mf][nf][2] * sc.z + sh.z;
                float y3 = acc[mf][nf][3] * sc.w + sh.w;
                if (RELU) {
                    y0 = fmaxf(y0, 0.f); y1 = fmaxf(y1, 0.f);
                    y2 = fmaxf(y2, 0.f); y3 = fmaxf(y3, 0.f);
                }
                ushort4 pk;
                pk.x = f2bf(y0); pk.y = f2bf(y1); pk.z = f2bf(y2); pk.w = f2bf(y3);
                *(ushort4*)(out + (size_t)row * HID + col) = pk;
            }
        }
    }
}

// ---------------- pooling + head ----------------

__global__ void k_bounds(const int* __restrict__ batch, int* __restrict__ bounds) {
    int t = threadIdx.x;
    if (t <= NG) {
        int lo = 0, hi = NN;
        while (lo < hi) { int mid = (lo + hi) >> 1; if (batch[mid] < t) lo = mid + 1; else hi = mid; }
        bounds[t] = lo;
    }
}

__global__ void k_pool(const unsigned short* __restrict__ x, const int* __restrict__ bounds,
                       float* __restrict__ pooled) {
    int g = blockIdx.x, s = blockIdx.y, t = threadIdx.x; // 512 thr
    int b0 = bounds[g], b1 = bounds[g + 1];
    int len = b1 - b0;
    int r0 = b0 + (int)((long long)len * s / 8);
    int r1 = b0 + (int)((long long)len * (s + 1) / 8);
    float acc = 0.f;
    for (int r = r0; r < r1; r++) acc += bf2f(x[(size_t)r * HID + t]);
    if (r1 > r0) atomicAdd(&pooled[g * HID + t], acc);
}

__global__ void k_head1(const float* __restrict__ pooled, const int* __restrict__ bounds,
                        const float* __restrict__ lin_w, const float* __restrict__ lin_b,
                        float* __restrict__ gout) {
    int g = blockIdx.x, t = threadIdx.x; // 512
    __shared__ float row[HID];
    int cnt = bounds[g + 1] - bounds[g];
    float invc = 1.f / fmaxf((float)cnt, 1.f);
    row[t] = pooled[g * HID + t] * invc;
    __syncthreads();
    float acc = lin_b[t];
    for (int k = 0; k < HID; k++) acc += row[k] * lin_w[(size_t)k * HID + t];
    gout[g * HID + t] = 0.5f * acc * (1.f + erff(acc * 0.7071067811865475f));
}

__global__ void k_head2(const float* __restrict__ gbuf, const float* __restrict__ clf_w,
                        const float* __restrict__ clf_b, float* __restrict__ out) {
    int g = blockIdx.x, t = threadIdx.x; // 128
    __shared__ float row[HID];
    for (int k = t; k < HID; k += 128) row[k] = gbuf[g * HID + k];
    __syncthreads();
    float acc = clf_b[t];
    for (int k = 0; k < HID; k++) acc += row[k] * clf_w[(size_t)k * COUT + t];
    out[g * COUT + t] = acc;
}

// ---------------- launch ----------------

extern "C" void kernel_launch(void* const* d_in, const int* in_sizes, int n_in,
                              void* d_out, int out_size, void* d_ws, size_t ws_size,
                              hipStream_t stream) {
    const float* x_f32   = (const float*)d_in[0];
    const int*   ei      = (const int*)d_in[1];
    const int*   batch   = (const int*)d_in[2];
    const float* enc_w   = (const float*)d_in[3];
    const float* enc_b   = (const float*)d_in[4];
    const float* conv_w0 = (const float*)d_in[5];
    const float* conv_b0 = (const float*)d_in[6];
    const float* bn0_g   = (const float*)d_in[7];
    const float* bn0_b   = (const float*)d_in[8];
    const float* conv_w1 = (const float*)d_in[9];
    const float* conv_b1 = (const float*)d_in[10];
    const float* bn1_g   = (const float*)d_in[11];
    const float* bn1_b   = (const float*)d_in[12];
    const float* lin_w   = (const float*)d_in[13];
    const float* lin_b   = (const float*)d_in[14];
    const float* clf_w   = (const float*)d_in[15];
    const float* clf_b   = (const float*)d_in[16];
    const int* srcp = ei;
    const int* dstp = ei + NE;

    char* ws = (char*)d_ws;
    size_t o = 0;
    auto alloc = [&](size_t b) { size_t r = o; o += (b + 255) & ~(size_t)255; return r; };
    unsigned short* buf0 = (unsigned short*)(ws + alloc((size_t)NN * HID * 2));
    unsigned short* buf1 = (unsigned short*)(ws + alloc((size_t)NN * HID * 2));
    unsigned short* buf2 = (unsigned short*)(ws + alloc((size_t)NN * HID * 2));
    unsigned short* xbf = buf1; // alias: encoder input dead before buf1's first real use
    unsigned short* encT = (unsigned short*)(ws + alloc((size_t)HID * CIN * 2));
    unsigned short* c0T  = (unsigned short*)(ws + alloc((size_t)2 * HID * HID * 2));
    unsigned short* c1T  = (unsigned short*)(ws + alloc((size_t)2 * HID * HID * 2));
    float* aff_scale = (float*)(ws + alloc(5 * HID * 4));
    float* aff_shift = (float*)(ws + alloc(5 * HID * 4));
    int* indeg  = (int*)(ws + alloc((size_t)NN * 4));
    int* off    = (int*)(ws + alloc((size_t)(NN + 1) * 4));
    int* cursor = (int*)(ws + alloc((size_t)NN * 4));
    int* csr    = (int*)(ws + alloc((size_t)NE * 4));
    int* scan_local = (int*)(ws + alloc((size_t)NN * 4));
    int* scan_bsum  = (int*)(ws + alloc((size_t)256 * 4));
    int* bounds = (int*)(ws + alloc((size_t)(NG + 1) * 4));
    float* pooled = (float*)(ws + alloc((size_t)NG * HID * 4));
    float* gbuf   = (float*)(ws + alloc((size_t)NG * HID * 4));
    (void)ws_size; (void)n_in; (void)in_sizes; (void)out_size;

    hipMemsetAsync(indeg, 0, (size_t)NN * 4, stream);
    hipMemsetAsync(pooled, 0, (size_t)NG * HID * 4, stream);

    // weight prep
    k_f32_to_bf16<<<(NN * CIN / 4 + 255) / 256, 256, 0, stream>>>(x_f32, xbf, NN * CIN / 4);
    k_transpose_cvt<<<dim3(HID / 32, CIN / 32), 256, 0, stream>>>(enc_w, encT, CIN, HID);
    k_transpose_cvt<<<dim3(16, 16), 256, 0, stream>>>(conv_w0, c0T, HID, HID);
    k_transpose_cvt<<<dim3(16, 16), 256, 0, stream>>>(conv_w0 + HID * HID, c0T + HID * HID, HID, HID);
    k_transpose_cvt<<<dim3(16, 16), 256, 0, stream>>>(conv_w1, c1T, HID, HID);
    k_transpose_cvt<<<dim3(16, 16), 256, 0, stream>>>(conv_w1 + HID * HID, c1T + HID * HID, HID, HID);
    k_affine<<<1, 512, 0, stream>>>(enc_b, conv_b0, bn0_g, bn0_b, conv_b1, bn1_g, bn1_b,
                                    aff_scale, aff_shift);

    // CSR (hierarchical scan)
    k_hist<<<(NE + 255) / 256, 256, 0, stream>>>(dstp, indeg, NE);
    k_scan1<<<SCAN_NB, 256, 0, stream>>>(indeg, scan_local, scan_bsum, NN);
    k_scan2<<<1, 256, 0, stream>>>(scan_bsum, SCAN_NB);
    k_scan3<<<SCAN_NB, 256, 0, stream>>>(scan_local, scan_bsum, indeg, off, cursor, NN);
    k_fill<<<(NE + 255) / 256, 256, 0, stream>>>(srcp, dstp, cursor, csr, NE);
    k_bounds<<<1, 128, 0, stream>>>(batch, bounds);

    const int gq = GEMM_NWG / 8, gr = GEMM_NWG % 8;

    // encoder (K=256)
    k_gemm<0><<<GEMM_NWG, 256, 0, stream>>>(xbf, encT, aff_scale, aff_shift, buf0, NN, CIN, gq, gr);

    // GIN layers (K=512)
    for (int l = 0; l < 2; l++) {
        k_aggregate<<<(NN * 64) / 256, 256, 0, stream>>>(buf0, off, csr, buf1);
        k_gemm<1><<<GEMM_NWG, 256, 0, stream>>>(buf1, c0T + (size_t)l * HID * HID,
                                                aff_scale + (1 + 2 * l) * HID, aff_shift + (1 + 2 * l) * HID,
                                                buf2, NN, HID, gq, gr);
        if (l == 0)
            k_gemm<1><<<GEMM_NWG, 256, 0, stream>>>(buf2, c1T + (size_t)l * HID * HID,
                                                    aff_scale + (2 + 2 * l) * HID, aff_shift + (2 + 2 * l) * HID,
                                                    buf0, NN, HID, gq, gr);
        else
            k_gemm<0><<<GEMM_NWG, 256, 0, stream>>>(buf2, c1T + (size_t)l * HID * HID,
                                                    aff_scale + (2 + 2 * l) * HID, aff_shift + (2 + 2 * l) * HID,
                                                    buf0, NN, HID, gq, gr);
    }

    // pool + head
    k_pool<<<dim3(NG, 8), 512, 0, stream>>>(buf0, bounds, pooled);
    k_head1<<<NG, 512, 0, stream>>>(pooled, bounds, lin_w, lin_b, gbuf);
    k_head2<<<NG, 128, 0, stream>>>(gbuf, clf_w, clf_b, (float*)d_out);
}